// Round 7
// baseline (3348.491 us; speedup 1.0000x reference)
//
#include <hip/hip_runtime.h>
#include <cmath>

// fusion_36455682409119 round 7:
//  - conv64_pipe v2: reg-staged T14 pipeline. Tile t+1's halo loaded to REGISTERS
//    (coalesced vector loads, legacy addressing) before COMPUTE(t); swizzled
//    ds_write after compute (one barrier/tile, dbuf 2x26KB LDS, NT=5).
//    (round-6 gload_lds failed: permuted per-lane source broke wave coalescing
//     -> 16x read amplification. Swizzle must live on the ds_write dest.)
//  - CIN=128 convs, final conv, mdcn, prep/transpose: round-5 proven path.

using short8 = __attribute__((ext_vector_type(8))) short;
using f32x4  = __attribute__((ext_vector_type(4))) float;

#define DEVINL static __device__ __forceinline__

DEVINL unsigned short f2bf(float f){
    unsigned u = __float_as_uint(f);
    u += 0x7fffu + ((u >> 16) & 1u);
    return (unsigned short)(u >> 16);
}
DEVINL unsigned pack2(float a, float b){ return (unsigned)f2bf(a) | ((unsigned)f2bf(b) << 16); }
DEVINL float bflo(unsigned u){ return __uint_as_float(u << 16); }
DEVINL float bfhi(unsigned u){ return __uint_as_float(u & 0xffff0000u); }
DEVINL float bf2f(unsigned short u){ return __uint_as_float((unsigned)u << 16); }
DEVINL float lrelu_f(float v){ return v >= 0.f ? v : 0.1f * v; }

// m204 bijective XCD swizzle
DEVINL void swz_decode(int& bx, int& by, int& bz){
    const int gx = gridDim.x, gy = gridDim.y;
    int lin = blockIdx.x + gx * (blockIdx.y + gy * blockIdx.z);
    int nwg = gx * gy * gridDim.z;
    int q = nwg >> 3, r = nwg & 7;
    int xcd = lin & 7, idx = lin >> 3;
    int swz = (xcd < r ? xcd * (q + 1) : r + xcd * q) + idx;
    bz = swz / (gx * gy);
    int rem = swz - bz * gx * gy;
    by = rem / gx; bx = rem - by * gx;
}

struct Ptr4 { unsigned short* p[4]; };

// ---------------- both NCHW f32 -> NHWC bf16 transposes in one launch ----------------
__global__ __launch_bounds__(256) void nchw2nhwc2(const float* __restrict__ inA,
                                                  const float* __restrict__ inB,
                                                  unsigned short* __restrict__ outA,
                                                  unsigned short* __restrict__ outB)
{
    constexpr int HW = 180 * 320;
    const int blk = blockIdx.x;
    const float* in = (blk < 900) ? inA : inB;
    unsigned short* out = (blk < 900) ? outA : outB;
    size_t idx = (size_t)(blk % 900) * 256 + threadIdx.x;
    size_t bb = idx / HW, p = idx % HW;
    const float* src = in + (bb * 64) * (size_t)HW + p;
    unsigned short* dst = out + idx * 64;
    #pragma unroll
    for (int c0 = 0; c0 < 64; c0 += 16) {
        unsigned r[8];
        #pragma unroll
        for (int q = 0; q < 8; ++q)
            r[q] = pack2(src[(size_t)(c0 + 2*q) * HW], src[(size_t)(c0 + 2*q + 1) * HW]);
        *(uint4*)(dst + c0)     = *(uint4*)&r[0];
        *(uint4*)(dst + c0 + 8) = *(uint4*)&r[4];
    }
}

// ---------------- all weight prepacks in one launch ----------------
struct PrepArgs {
    const float* src[11];
    unsigned short* dst[11];
    int cout[11]; int cin[11]; int nch[11]; int kind[11];
};

__global__ __launch_bounds__(256) void prep_all(PrepArgs a)
{
    const int t = blockIdx.y;
    const int idx = blockIdx.x * 256 + threadIdx.x;
    if (a.kind[t] == 1) {
        if (idx >= 36864) return;
        int kk = idx & 31, oc = (idx >> 5) & 63, s = idx >> 11;
        int k = s * 32 + kk;
        int gt = k >> 3, c8 = k & 7;
        int g = gt / 9, tp = gt - g * 9;
        a.dst[t][idx] = f2bf(a.src[t][((size_t)oc * 64 + g * 8 + c8) * 9 + tp]);
    } else {
        int cin = a.cin[t], cout = a.cout[t];
        int ncs = cin / 32;
        int total = a.nch[t] * 9 * ncs * 2048;
        if (idx >= total) return;
        int kk = idx & 31, oc_l = (idx >> 5) & 63, rest = idx >> 11;
        int cs = rest % ncs; int rest2 = rest / ncs;
        int j = rest2 % 9; int ch = rest2 / 9;
        int oc = ch * 64 + oc_l, c = cs * 32 + kk;
        float v = (oc < cout) ? a.src[t][((size_t)oc * cin + c) * 9 + j] : 0.f;
        a.dst[t][idx] = f2bf(v);
    }
}

// ---------------- legacy single-phase conv (CIN=128 convs + final OUTMODE 2) ----------------
template<int CIN, bool TWO_IN, bool ACT, bool SCALE, int OUTMODE, int NM>
__global__ __launch_bounds__(256, (CIN == 128 ? 2 : 3)) void conv_mfma(
    const unsigned short* __restrict__ in0, const unsigned short* __restrict__ in1,
    const unsigned short* __restrict__ wgt, const float* __restrict__ bias,
    unsigned short* __restrict__ out, const float* __restrict__ corr,
    const float* __restrict__ res, float* __restrict__ outf,
    Ptr4 omout, int choff, int zdiv, int COUT)
{
    constexpr int H = 180, W = 320, HW = H * W;
    constexpr int NCB = CIN / 8;
    constexpr int NCS = CIN / 32;
    __shared__ __align__(16) unsigned char lds[6 * 34 * CIN * 2];

    const int tid = threadIdx.x;
    int bx, by, bz;
    swz_decode(bx, by, bz);
    int b, ch;
    if (OUTMODE == 1) { b = bz / zdiv; ch = bz % zdiv + choff; }
    else              { b = bz; ch = 0; }
    const int x0 = bx * 32, y0 = by * 4;

    for (int t = tid; t < 6 * 34 * NCB; t += 256) {
        int cb = t % NCB; int r = t / NCB;
        int xp = r % 34, yp = r / 34;
        int gx = x0 - 1 + xp, gy = y0 - 1 + yp;
        uint4 v = make_uint4(0, 0, 0, 0);
        if (gx >= 0 && gx < W && gy >= 0 && gy < H) {
            size_t pix = (size_t)b * HW + (size_t)gy * W + gx;
            const unsigned short* src;
            if (TWO_IN) src = (cb < 8) ? (in0 + pix * 64 + cb * 8) : (in1 + pix * 64 + (cb - 8) * 8);
            else        src = in0 + pix * CIN + cb * 8;
            v = *(const uint4*)src;
            if (SCALE) {
                float cv = corr[pix];
                v.x = pack2(bflo(v.x) * cv, bfhi(v.x) * cv);
                v.y = pack2(bflo(v.y) * cv, bfhi(v.y) * cv);
                v.z = pack2(bflo(v.z) * cv, bfhi(v.z) * cv);
                v.w = pack2(bflo(v.w) * cv, bfhi(v.w) * cv);
            }
        }
        int blk = cb ^ (xp & 7);
        *(uint4*)&lds[(size_t)((yp * 34 + xp) * NCB + blk) * 16] = v;
    }
    __syncthreads();

    const int wv = tid >> 6, lane = tid & 63;
    const int ll = lane & 15, lh = lane >> 4;
    const unsigned short* wchunk = wgt + (size_t)ch * (9 * NCS * 2048);
    const int alane = ll * 32 + lh * 8;

    f32x4 acc[NM][2];
    #pragma unroll
    for (int mi = 0; mi < NM; ++mi)
        #pragma unroll
        for (int nf = 0; nf < 2; ++nf) acc[mi][nf] = f32x4{0.f, 0.f, 0.f, 0.f};

    #pragma unroll
    for (int j = 0; j < 9; ++j) {
        const int jy = j / 3, jx = j % 3;
        #pragma unroll
        for (int cs = 0; cs < NCS; ++cs) {
            const int s = j * NCS + cs;
            short8 a[NM];
            #pragma unroll
            for (int mi = 0; mi < NM; ++mi)
                a[mi] = *(const short8*)(wchunk + (size_t)s * 2048 + mi * 512 + alane);
            short8 bf[2];
            #pragma unroll
            for (int nf = 0; nf < 2; ++nf) {
                int xp = nf * 16 + ll + jx;
                int blk = (cs * 4 + lh) ^ (xp & 7);
                int addr = (((wv + jy) * 34 + xp) * NCB + blk) * 16;
                bf[nf] = *(const short8*)&lds[addr];
            }
            #pragma unroll
            for (int mi = 0; mi < NM; ++mi)
                #pragma unroll
                for (int nf = 0; nf < 2; ++nf)
                    acc[mi][nf] = __builtin_amdgcn_mfma_f32_16x16x32_bf16(a[mi], bf[nf], acc[mi][nf], 0, 0, 0);
        }
    }

    const int py = y0 + wv;
    const size_t pixrow = (size_t)b * HW + (size_t)py * W;
    #pragma unroll
    for (int nf = 0; nf < 2; ++nf) {
        const int px = x0 + nf * 16 + ll;
        if (OUTMODE == 3) {
            float dot = 0.f;
            const unsigned* er = (const unsigned*)(in1 + (pixrow + px) * 64);
            #pragma unroll
            for (int mi = 0; mi < NM; ++mi) {
                const int oc_l = mi * 16 + lh * 4;
                unsigned e0 = er[oc_l / 2], e1 = er[oc_l / 2 + 1];
                float t0 = acc[mi][nf][0] + bias[oc_l + 0];
                float t1 = acc[mi][nf][1] + bias[oc_l + 1];
                float t2 = acc[mi][nf][2] + bias[oc_l + 2];
                float t3 = acc[mi][nf][3] + bias[oc_l + 3];
                dot += t0 * bflo(e0) + t1 * bfhi(e0) + t2 * bflo(e1) + t3 * bfhi(e1);
            }
            dot += __shfl_xor(dot, 16);
            dot += __shfl_xor(dot, 32);
            if (lh == 0) outf[pixrow + px] = dot;
        } else if (OUTMODE == 1) {
            unsigned short* oslot = omout.p[b];
            #pragma unroll
            for (int mi = 0; mi < NM; ++mi) {
                const int oc_l = mi * 16 + lh * 4;
                #pragma unroll
                for (int jj = 0; jj < 4; ++jj) {
                    int ocg = ch * 64 + oc_l + jj;
                    if (ocg < COUT) {
                        float t = acc[mi][nf][jj] + bias[ocg];
                        oslot[(size_t)ocg * HW + (size_t)py * W + px] = f2bf(ACT ? lrelu_f(t) : t);
                    }
                }
            }
        } else {
            #pragma unroll
            for (int mi = 0; mi < NM; ++mi) {
                const int oc_l = mi * 16 + lh * 4;
                if (OUTMODE == 0) {
                    float v[4];
                    #pragma unroll
                    for (int jj = 0; jj < 4; ++jj) {
                        float t = acc[mi][nf][jj] + bias[oc_l + jj];
                        v[jj] = ACT ? lrelu_f(t) : t;
                    }
                    uint2 st; st.x = pack2(v[0], v[1]); st.y = pack2(v[2], v[3]);
                    *(uint2*)&out[(pixrow + px) * 64 + oc_l] = st;
                } else {
                    #pragma unroll
                    for (int jj = 0; jj < 4; ++jj) {
                        int oc = oc_l + jj;
                        float t = acc[mi][nf][jj] + bias[oc];
                        if (ACT) t = lrelu_f(t);
                        size_t idx = ((size_t)b * 64 + oc) * HW + (size_t)py * W + px;
                        outf[idx] = t + res[idx];
                    }
                }
            }
        }
    }
}

// ---------------- pipelined CIN=64 conv v2: reg-staged, NT=5, dbuf, 1 barrier/tile ----------------
// OUTMODE 0: bf16 NHWC. 1: bf16 planar omout.p[b]. 3: corr dot -> outf.
template<bool ACT, int OUTMODE, int NM>
__global__ __launch_bounds__(256, 3) void conv64_pipe(
    const unsigned short* __restrict__ in0, const unsigned short* __restrict__ in1,
    const unsigned short* __restrict__ wgt, const float* __restrict__ bias,
    unsigned short* __restrict__ out, float* __restrict__ outf,
    Ptr4 omout, int choff, int zdiv)
{
    constexpr int H = 180, W = 320, HW = H * W;
    constexpr int NT = 5;
    constexpr int NE = 6 * 34 * 8;   // 1632 16B elements per halo
    __shared__ __align__(16) unsigned char lds2[2][6 * 34 * 8 * 16];   // 2 x 26112 B

    const int tid = threadIdx.x;
    int bx, by, bz;
    swz_decode(bx, by, bz);
    int b, ch;
    if (OUTMODE == 1) { b = bz / zdiv; ch = bz % zdiv + choff; }
    else              { b = bz; ch = 0; }
    const int x0 = bx * 32;
    const int yb0 = by * (NT * 4);

    const unsigned short* inb = in0 + (size_t)b * HW * 64;

    // per-thread staging slots (legacy addressing: cb fastest -> coalesced loads)
    int ypq[7], ldsoff[7];
    bool liveq[7], okq[7];
    const unsigned short* colp[7];
    #pragma unroll
    for (int q = 0; q < 7; ++q) {
        int e = tid + 256 * q;
        bool live = e < NE;
        int cb = e & 7; int r = e >> 3;
        int xp = r % 34, yp = r / 34;
        int gx = x0 - 1 + xp;
        ypq[q] = yp;
        liveq[q] = live;
        okq[q] = live && gx >= 0 && gx < W;
        colp[q] = inb + (size_t)gx * 64 + cb * 8;
        ldsoff[q] = ((yp * 34 + xp) * 8 + (cb ^ (xp & 7))) * 16;
    }

    uint4 v[7];
    auto REG_LOAD = [&](int t){
        int gyb = yb0 + t * 4 - 1;
        #pragma unroll
        for (int q = 0; q < 7; ++q) {
            int gy = gyb + ypq[q];
            v[q] = (okq[q] && gy >= 0 && gy < H)
                 ? *(const uint4*)(colp[q] + (size_t)gy * (W * 64))
                 : make_uint4(0, 0, 0, 0);
        }
    };
    auto DS_WRITE = [&](int buf){
        #pragma unroll
        for (int q = 0; q < 7; ++q)
            if (liveq[q]) *(uint4*)&lds2[buf][ldsoff[q]] = v[q];
    };

    const int wv = tid >> 6, lane = tid & 63;
    const int ll = lane & 15, lh = lane >> 4;
    const unsigned short* wchunk = wgt + (size_t)ch * (9 * 2 * 2048);
    const int alane = ll * 32 + lh * 8;

    REG_LOAD(0);
    DS_WRITE(0);

    int buf = 0;
    for (int t = 0; t < NT; ++t) {
        if (t + 1 < NT) REG_LOAD(t + 1);    // issue early: latency hides under MFMA
        __syncthreads();                     // prev DS_WRITE visible; buf^1 free

        const unsigned char* lds = (const unsigned char*)lds2[buf];
        f32x4 acc[NM][2];
        #pragma unroll
        for (int mi = 0; mi < NM; ++mi)
            #pragma unroll
            for (int nf = 0; nf < 2; ++nf) acc[mi][nf] = f32x4{0.f, 0.f, 0.f, 0.f};

        #pragma unroll
        for (int j = 0; j < 9; ++j) {
            const int jy = j / 3, jx = j % 3;
            #pragma unroll
            for (int cs = 0; cs < 2; ++cs) {
                const int s = j * 2 + cs;
                short8 a[NM];
                #pragma unroll
                for (int mi = 0; mi < NM; ++mi)
                    a[mi] = *(const short8*)(wchunk + (size_t)s * 2048 + mi * 512 + alane);
                short8 bf[2];
                #pragma unroll
                for (int nf = 0; nf < 2; ++nf) {
                    int xp = nf * 16 + ll + jx;
                    int blk = (cs * 4 + lh) ^ (xp & 7);
                    int addr = (((wv + jy) * 34 + xp) * 8 + blk) * 16;
                    bf[nf] = *(const short8*)&lds[addr];
                }
                #pragma unroll
                for (int mi = 0; mi < NM; ++mi)
                    #pragma unroll
                    for (int nf = 0; nf < 2; ++nf)
                        acc[mi][nf] = __builtin_amdgcn_mfma_f32_16x16x32_bf16(a[mi], bf[nf], acc[mi][nf], 0, 0, 0);
            }
        }

        const int py = yb0 + t * 4 + wv;
        const size_t pixrow = (size_t)b * HW + (size_t)py * W;
        #pragma unroll
        for (int nf = 0; nf < 2; ++nf) {
            const int px = x0 + nf * 16 + ll;
            if (OUTMODE == 3) {
                float dot = 0.f;
                const unsigned* er = (const unsigned*)(in1 + (pixrow + px) * 64);
                #pragma unroll
                for (int mi = 0; mi < NM; ++mi) {
                    const int oc_l = mi * 16 + lh * 4;
                    unsigned e0 = er[oc_l / 2], e1 = er[oc_l / 2 + 1];
                    float t0 = acc[mi][nf][0] + bias[oc_l + 0];
                    float t1 = acc[mi][nf][1] + bias[oc_l + 1];
                    float t2 = acc[mi][nf][2] + bias[oc_l + 2];
                    float t3 = acc[mi][nf][3] + bias[oc_l + 3];
                    dot += t0 * bflo(e0) + t1 * bfhi(e0) + t2 * bflo(e1) + t3 * bfhi(e1);
                }
                dot += __shfl_xor(dot, 16);
                dot += __shfl_xor(dot, 32);
                if (lh == 0) outf[pixrow + px] = dot;
            } else if (OUTMODE == 1) {
                unsigned short* oslot = omout.p[b];
                #pragma unroll
                for (int mi = 0; mi < NM; ++mi) {
                    const int oc_l = mi * 16 + lh * 4;
                    #pragma unroll
                    for (int jj = 0; jj < 4; ++jj) {
                        int ocg = ch * 64 + oc_l + jj;
                        if (ocg < 216) {
                            float tv = acc[mi][nf][jj] + bias[ocg];
                            oslot[(size_t)ocg * HW + (size_t)py * W + px] = f2bf(ACT ? lrelu_f(tv) : tv);
                        }
                    }
                }
            } else {
                #pragma unroll
                for (int mi = 0; mi < NM; ++mi) {
                    const int oc_l = mi * 16 + lh * 4;
                    float vv[4];
                    #pragma unroll
                    for (int jj = 0; jj < 4; ++jj) {
                        float tv = acc[mi][nf][jj] + bias[oc_l + jj];
                        vv[jj] = ACT ? lrelu_f(tv) : tv;
                    }
                    uint2 st; st.x = pack2(vv[0], vv[1]); st.y = pack2(vv[2], vv[3]);
                    *(uint2*)&out[(pixrow + px) * 64 + oc_l] = st;
                }
            }
        }

        if (t + 1 < NT) DS_WRITE(buf ^ 1);   // vmcnt drained here, after compute
        buf ^= 1;
    }
}

// ---------------- mdcn v2 (dg=8, Cg=8, 64->64), XCD-swizzled ----------------
template<int ACT>
__global__ __launch_bounds__(256, 4) void mdcn_mfma(
    const unsigned short* __restrict__ x, size_t xstride,
    const unsigned short* __restrict__ om, size_t omstride,
    const unsigned short* __restrict__ wgt, const float* __restrict__ bias,
    unsigned short* __restrict__ out, size_t ostride)
{
    constexpr int H = 180, W = 320, HW = H * W;
    __shared__ __align__(16) unsigned char sv[72 * 32 * 16];

    const int tid = threadIdx.x;
    int bx, by, bz;
    swz_decode(bx, by, bz);
    const unsigned short* xb  = x  + (size_t)bz * xstride;
    const unsigned short* omb = om + (size_t)bz * omstride;
    unsigned short* ob        = out + (size_t)bz * ostride;
    const int px0 = bx * 32;
    const int py  = by;

    {
        const int pxl = tid & 31, g = tid >> 5;
        const int px = px0 + pxl;
        const size_t p = (size_t)py * W + px;
        const unsigned short* omg = omb + (size_t)(g * 9) * HW + p;

        float oyv[9], oxv[9], mmv[9];
        #pragma unroll
        for (int k = 0; k < 9; ++k) oyv[k] = bf2f(omg[(size_t)k * HW]);
        #pragma unroll
        for (int k = 0; k < 9; ++k) oxv[k] = bf2f(omg[(size_t)(72 + k) * HW]);
        #pragma unroll
        for (int k = 0; k < 9; ++k) mmv[k] = bf2f(omg[(size_t)(144 + k) * HW]);

        #pragma unroll
        for (int k = 0; k < 9; ++k) {
            float m = 1.f / (1.f + __expf(-mmv[k]));
            float pyf = (float)(py + (k / 3) - 1) + oyv[k];
            float pxf = (float)(px + (k % 3) - 1) + oxv[k];
            float y0f = floorf(pyf), x0f = floorf(pxf);
            float wy = pyf - y0f, wx = pxf - x0f;
            int yi = (int)y0f, xi = (int)x0f;
            bool vy0 = (yi >= 0) && (yi < H);
            bool vy1 = (yi + 1 >= 0) && (yi + 1 < H);
            bool vx0 = (xi >= 0) && (xi < W);
            bool vx1 = (xi + 1 >= 0) && (xi + 1 < W);
            float w00 = (vy0 && vx0) ? (1.f - wy) * (1.f - wx) * m : 0.f;
            float w01 = (vy0 && vx1) ? (1.f - wy) * wx * m : 0.f;
            float w10 = (vy1 && vx0) ? wy * (1.f - wx) * m : 0.f;
            float w11 = (vy1 && vx1) ? wy * wx * m : 0.f;
            int yc0 = min(max(yi, 0), H - 1), yc1 = min(max(yi + 1, 0), H - 1);
            int xc0 = min(max(xi, 0), W - 1), xc1 = min(max(xi + 1, 0), W - 1);
            uint4 c00 = *(const uint4*)(xb + ((size_t)(yc0 * W + xc0) * 64 + g * 8));
            uint4 c01 = *(const uint4*)(xb + ((size_t)(yc0 * W + xc1) * 64 + g * 8));
            uint4 c10 = *(const uint4*)(xb + ((size_t)(yc1 * W + xc0) * 64 + g * 8));
            uint4 c11 = *(const uint4*)(xb + ((size_t)(yc1 * W + xc1) * 64 + g * 8));
            const unsigned* p00 = (const unsigned*)&c00;
            const unsigned* p01 = (const unsigned*)&c01;
            const unsigned* p10 = (const unsigned*)&c10;
            const unsigned* p11 = (const unsigned*)&c11;
            unsigned r[4];
            #pragma unroll
            for (int q = 0; q < 4; ++q) {
                float lo = w00 * bflo(p00[q]) + w01 * bflo(p01[q]) + w10 * bflo(p10[q]) + w11 * bflo(p11[q]);
                float hi = w00 * bfhi(p00[q]) + w01 * bfhi(p01[q]) + w10 * bfhi(p10[q]) + w11 * bfhi(p11[q]);
                r[q] = pack2(lo, hi);
            }
            *(uint4*)&sv[(size_t)((g * 9 + k) * 32 + pxl) * 16] = *(uint4*)r;
        }
    }
    __syncthreads();

    const int wv = tid >> 6, lane = tid & 63;
    const int ll = lane & 15, lh = lane >> 4;
    f32x4 acc[2] = {f32x4{0.f,0.f,0.f,0.f}, f32x4{0.f,0.f,0.f,0.f}};
    #pragma unroll
    for (int s = 0; s < 18; ++s) {
        short8 a = *(const short8*)(wgt + (size_t)(s * 64 + wv * 16 + ll) * 32 + lh * 8);
        #pragma unroll
        for (int nf = 0; nf < 2; ++nf) {
            short8 bb = *(const short8*)&sv[(size_t)s * 2048 + lh * 512 + (nf * 16 + ll) * 16];
            acc[nf] = __builtin_amdgcn_mfma_f32_16x16x32_bf16(a, bb, acc[nf], 0, 0, 0);
        }
    }
    #pragma unroll
    for (int nf = 0; nf < 2; ++nf) {
        int opx = px0 + nf * 16 + ll;
        int oc0 = wv * 16 + lh * 4;
        float v[4];
        #pragma unroll
        for (int jj = 0; jj < 4; ++jj) {
            float t = acc[nf][jj] + bias[oc0 + jj];
            v[jj] = ACT ? lrelu_f(t) : t;
        }
        uint2 st; st.x = pack2(v[0], v[1]); st.y = pack2(v[2], v[3]);
        *(uint2*)&ob[((size_t)py * W + opx) * 64 + oc0] = st;
    }
}

extern "C" void kernel_launch(void* const* d_in, const int* in_sizes, int n_in,
                              void* d_out, int out_size, void* d_ws, size_t ws_size,
                              hipStream_t stream)
{
    const float* ref    = (const float*)d_in[0];
    const float* neb    = (const float*)d_in[1];
    const float* w_oc1  = (const float*)d_in[2];  const float* b_oc1  = (const float*)d_in[3];
    const float* w_om1  = (const float*)d_in[4];  const float* b_om1  = (const float*)d_in[5];
    const float* w_dcn1 = (const float*)d_in[6];  const float* b_dcn1 = (const float*)d_in[7];
    const float* w_fc   = (const float*)d_in[8];  const float* b_fc   = (const float*)d_in[9];
    const float* w_cas1 = (const float*)d_in[10]; const float* b_cas1 = (const float*)d_in[11];
    const float* w_cas2 = (const float*)d_in[12]; const float* b_cas2 = (const float*)d_in[13];
    const float* w_om2  = (const float*)d_in[14]; const float* b_om2  = (const float*)d_in[15];
    const float* w_dcn2 = (const float*)d_in[16]; const float* b_dcn2 = (const float*)d_in[17];
    const float* w_ta1  = (const float*)d_in[18]; const float* b_ta1  = (const float*)d_in[19];
    const float* w_ta2  = (const float*)d_in[20]; const float* b_ta2  = (const float*)d_in[21];
    const float* w_ff   = (const float*)d_in[22]; const float* b_ff   = (const float*)d_in[23];

    constexpr int H = 180, W = 320, HW = H * W;
    constexpr size_t CHW = (size_t)HW * 64;
    constexpr size_t SLB = 4 * CHW * 2;
    constexpr size_t OMSLOT_EL = (size_t)HW * 216;
    constexpr size_t OMSLOT_B  = OMSLOT_EL * 2;

    char* wsb = (char*)d_ws;
    unsigned short* S0 = (unsigned short*)(wsb);
    unsigned short* S1 = (unsigned short*)(wsb + SLB);
    unsigned short* S2 = (unsigned short*)(wsb + 2 * SLB);
    unsigned short* S3 = (unsigned short*)(wsb + 3 * SLB);
    float* corrf = (float*)S3;
    unsigned short* ffw = (unsigned short*)(wsb + SLB + (2u << 20));

    char* doutb = (char*)d_out;
    unsigned short* omA0 = (unsigned short*)doutb;
    unsigned short* omA1 = omA0 + OMSLOT_EL;
    unsigned short* wb   = (unsigned short*)(doutb + 2 * OMSLOT_B);
    const bool big = ws_size >= 4 * SLB + 2 * OMSLOT_B;
    unsigned short* omB0 = (unsigned short*)(wsb + 4 * SLB);
    unsigned short* omB1 = omB0 + OMSLOT_EL;

    unsigned short* w_oc1p = wb + 0;
    unsigned short* w_om1p = wb + 73728;
    unsigned short* w_dcn1p= wb + 221184;
    unsigned short* w_fcp  = wb + 258048;
    unsigned short* w_cas1p= wb + 294912;
    unsigned short* w_cas2p= wb + 368640;
    unsigned short* w_om2p = wb + 405504;
    unsigned short* w_dcn2p= wb + 552960;
    unsigned short* w_ta1p = wb + 589824;
    unsigned short* w_ta2p = wb + 626688;
    unsigned short* w_ffp  = wb + 663552;

    dim3 blk(256);
    dim3 gp(10, 9, 4);        // pipelined conv grid (NT=5 tiles/block)
    dim3 g4(10, 45, 4);       // legacy grid
    dim3 gm(10, 180, 2);
    Ptr4 none{};

    nchw2nhwc2<<<1800, blk, 0, stream>>>(ref, neb, S0, S1);

    {
        PrepArgs pa;
        const float* srcs[11] = {w_oc1, w_om1, w_dcn1, w_fc, w_cas1, w_cas2, w_om2, w_dcn2, w_ta1, w_ta2, w_ff};
        unsigned short* dsts[11] = {w_oc1p, w_om1p, w_dcn1p, w_fcp, w_cas1p, w_cas2p, w_om2p, w_dcn2p, w_ta1p, w_ta2p, w_ffp};
        int couts[11] = {64, 216, 0, 64, 64, 64, 216, 0, 64, 64, 64};
        int cins[11]  = {128, 64, 0, 64, 128, 64, 64, 0, 64, 64, 64};
        int nchs[11]  = {1, 4, 0, 1, 1, 1, 4, 0, 1, 1, 1};
        int kinds[11] = {0, 0, 1, 0, 0, 0, 0, 1, 0, 0, 0};
        for (int i = 0; i < 11; ++i) {
            pa.src[i] = srcs[i]; pa.dst[i] = dsts[i];
            pa.cout[i] = couts[i]; pa.cin[i] = cins[i]; pa.nch[i] = nchs[i]; pa.kind[i] = kinds[i];
        }
        prep_all<<<dim3(576, 11), blk, 0, stream>>>(pa);
    }

    // 1. off1 = lrelu(conv(concat(neb,ref))) -> S2   (CIN=128: legacy)
    conv_mfma<128, true, true, false, 0, 4><<<g4, blk, 0, stream>>>(
        S1, S0, w_oc1p, b_oc1, S2, nullptr, nullptr, nullptr, none, 0, 1, 64);

    // om conv: chunks 0-2 (NM=4) + chunk 3 tail (NM=2), pipelined path
    auto ompack = [&](const unsigned short* inp, const unsigned short* wp, const float* bp,
                      Ptr4 slots, int nb){
        conv64_pipe<false, 1, 4><<<dim3(10, 9, 3 * nb), blk, 0, stream>>>(
            inp, nullptr, wp, bp, nullptr, nullptr, slots, 0, 3);
        conv64_pipe<false, 1, 2><<<dim3(10, 9, nb), blk, 0, stream>>>(
            inp, nullptr, wp, bp, nullptr, nullptr, slots, 3, 1);
    };

    // 2. pack1: om1 = conv(off1) [planar]; feat1 = mdcn(neb_t, om1) -> S3
    if (big) {
        Ptr4 slots{omA0, omA1, omB0, omB1};
        ompack(S2, w_om1p, b_om1, slots, 4);
        mdcn_mfma<0><<<gm, blk, 0, stream>>>(S1, CHW, omA0, OMSLOT_EL, w_dcn1p, b_dcn1, S3, CHW);
        mdcn_mfma<0><<<gm, blk, 0, stream>>>(S1 + 2 * CHW, CHW, omB0, OMSLOT_EL, w_dcn1p, b_dcn1, S3 + 2 * CHW, CHW);
    } else {
        Ptr4 slots{omA0, omA1, nullptr, nullptr};
        for (int pp = 0; pp < 2; ++pp) {
            ompack(S2 + 2 * pp * CHW, w_om1p, b_om1, slots, 2);
            mdcn_mfma<0><<<gm, blk, 0, stream>>>(S1 + 2 * pp * CHW, CHW, omA0, OMSLOT_EL,
                                                 w_dcn1p, b_dcn1, S3 + 2 * pp * CHW, CHW);
        }
    }

    // 3. feat2 = lrelu(conv(feat1)) -> S2   (pipelined)
    conv64_pipe<true, 0, 4><<<gp, blk, 0, stream>>>(
        S3, nullptr, w_fcp, b_fc, S2, nullptr, none, 0, 1);
    // 4. cas_a = lrelu(conv(concat(feat2,ref))) -> S1  (CIN=128: legacy)
    conv_mfma<128, true, true, false, 0, 4><<<g4, blk, 0, stream>>>(
        S2, S0, w_cas1p, b_cas1, S1, nullptr, nullptr, nullptr, none, 0, 1, 64);
    // 5. off2 = lrelu(conv(cas_a)) -> S3   (pipelined)
    conv64_pipe<true, 0, 4><<<gp, blk, 0, stream>>>(
        S1, nullptr, w_cas2p, b_cas2, S3, nullptr, none, 0, 1);

    // 6. pack2: om2 = conv(off2); feat3 = lrelu(mdcn(feat2, om2)) -> S1
    if (big) {
        Ptr4 slots{omA0, omA1, omB0, omB1};
        ompack(S3, w_om2p, b_om2, slots, 4);
        mdcn_mfma<1><<<gm, blk, 0, stream>>>(S2, CHW, omA0, OMSLOT_EL, w_dcn2p, b_dcn2, S1, CHW);
        mdcn_mfma<1><<<gm, blk, 0, stream>>>(S2 + 2 * CHW, CHW, omB0, OMSLOT_EL, w_dcn2p, b_dcn2, S1 + 2 * CHW, CHW);
    } else {
        Ptr4 slots{omA0, omA1, nullptr, nullptr};
        for (int pp = 0; pp < 2; ++pp) {
            ompack(S3 + 2 * pp * CHW, w_om2p, b_om2, slots, 2);
            mdcn_mfma<1><<<gm, blk, 0, stream>>>(S2 + 2 * pp * CHW, CHW, omA0, OMSLOT_EL,
                                                 w_dcn2p, b_dcn2, S1 + 2 * pp * CHW, CHW);
        }
    }

    // 7. emb_ref = conv(ref_t, ta1) -> S2 ; corr = dot(conv(feat3, ta2), emb_ref) (fused)
    conv64_pipe<false, 0, 4><<<gp, blk, 0, stream>>>(
        S0, nullptr, w_ta1p, b_ta1, S2, nullptr, none, 0, 1);
    conv64_pipe<false, 3, 4><<<gp, blk, 0, stream>>>(
        S1, S2, w_ta2p, b_ta2, nullptr, corrf, none, 0, 1);

    // relocate ff weights out of d_out before the final conv overwrites it
    hipMemcpyAsync(ffw, w_ffp, 36864 * 2, hipMemcpyDeviceToDevice, stream);

    // 8. out = lrelu(conv(ref_t*corr, ff)) + ref  (f32 NCHW into d_out)
    conv_mfma<64, false, true, true, 2, 4><<<g4, blk, 0, stream>>>(
        S0, nullptr, ffw, b_ff, nullptr, corrf, ref, (float*)d_out, none, 0, 1, 64);
}

// Round 8
// 1165.705 us; speedup vs baseline: 2.8725x; 2.8725x over previous
//
#include <hip/hip_runtime.h>
#include <cmath>

// fusion_36455682409119 round 8: round-5 proven structure (1185us) + depth-2
// register prefetch of MFMA A-fragments (weight loads) in conv_mfma and mdcn.
// Rounds 6/7 post-mortem: reg-staged pipeline kernels spilled staging state to
// scratch (FETCH 45MB -> 812MB) -> reverted. VGPR=40 in round-5 proved the
// compiler kept zero weight-load lookahead; abuf[3][NM] fixes that surgically.

using short8 = __attribute__((ext_vector_type(8))) short;
using f32x4  = __attribute__((ext_vector_type(4))) float;

#define DEVINL static __device__ __forceinline__

DEVINL unsigned short f2bf(float f){
    unsigned u = __float_as_uint(f);
    u += 0x7fffu + ((u >> 16) & 1u);
    return (unsigned short)(u >> 16);
}
DEVINL unsigned pack2(float a, float b){ return (unsigned)f2bf(a) | ((unsigned)f2bf(b) << 16); }
DEVINL float bflo(unsigned u){ return __uint_as_float(u << 16); }
DEVINL float bfhi(unsigned u){ return __uint_as_float(u & 0xffff0000u); }
DEVINL float bf2f(unsigned short u){ return __uint_as_float((unsigned)u << 16); }
DEVINL float lrelu_f(float v){ return v >= 0.f ? v : 0.1f * v; }

// m204 bijective XCD swizzle
DEVINL void swz_decode(int& bx, int& by, int& bz){
    const int gx = gridDim.x, gy = gridDim.y;
    int lin = blockIdx.x + gx * (blockIdx.y + gy * blockIdx.z);
    int nwg = gx * gy * gridDim.z;
    int q = nwg >> 3, r = nwg & 7;
    int xcd = lin & 7, idx = lin >> 3;
    int swz = (xcd < r ? xcd * (q + 1) : r + xcd * q) + idx;
    bz = swz / (gx * gy);
    int rem = swz - bz * gx * gy;
    by = rem / gx; bx = rem - by * gx;
}

struct Ptr4 { unsigned short* p[4]; };

// ---------------- both NCHW f32 -> NHWC bf16 transposes in one launch ----------------
__global__ __launch_bounds__(256) void nchw2nhwc2(const float* __restrict__ inA,
                                                  const float* __restrict__ inB,
                                                  unsigned short* __restrict__ outA,
                                                  unsigned short* __restrict__ outB)
{
    constexpr int HW = 180 * 320;
    const int blk = blockIdx.x;
    const float* in = (blk < 900) ? inA : inB;
    unsigned short* out = (blk < 900) ? outA : outB;
    size_t idx = (size_t)(blk % 900) * 256 + threadIdx.x;
    size_t bb = idx / HW, p = idx % HW;
    const float* src = in + (bb * 64) * (size_t)HW + p;
    unsigned short* dst = out + idx * 64;
    #pragma unroll
    for (int c0 = 0; c0 < 64; c0 += 16) {
        unsigned r[8];
        #pragma unroll
        for (int q = 0; q < 8; ++q)
            r[q] = pack2(src[(size_t)(c0 + 2*q) * HW], src[(size_t)(c0 + 2*q + 1) * HW]);
        *(uint4*)(dst + c0)     = *(uint4*)&r[0];
        *(uint4*)(dst + c0 + 8) = *(uint4*)&r[4];
    }
}

// ---------------- all weight prepacks in one launch ----------------
struct PrepArgs {
    const float* src[11];
    unsigned short* dst[11];
    int cout[11]; int cin[11]; int nch[11]; int kind[11];
};

__global__ __launch_bounds__(256) void prep_all(PrepArgs a)
{
    const int t = blockIdx.y;
    const int idx = blockIdx.x * 256 + threadIdx.x;
    if (a.kind[t] == 1) {
        if (idx >= 36864) return;
        int kk = idx & 31, oc = (idx >> 5) & 63, s = idx >> 11;
        int k = s * 32 + kk;
        int gt = k >> 3, c8 = k & 7;
        int g = gt / 9, tp = gt - g * 9;
        a.dst[t][idx] = f2bf(a.src[t][((size_t)oc * 64 + g * 8 + c8) * 9 + tp]);
    } else {
        int cin = a.cin[t], cout = a.cout[t];
        int ncs = cin / 32;
        int total = a.nch[t] * 9 * ncs * 2048;
        if (idx >= total) return;
        int kk = idx & 31, oc_l = (idx >> 5) & 63, rest = idx >> 11;
        int cs = rest % ncs; int rest2 = rest / ncs;
        int j = rest2 % 9; int ch = rest2 / 9;
        int oc = ch * 64 + oc_l, c = cs * 32 + kk;
        float v = (oc < cout) ? a.src[t][((size_t)oc * cin + c) * 9 + j] : 0.f;
        a.dst[t][idx] = f2bf(v);
    }
}

// ---------------- MFMA conv 3x3 SAME, tile (NM*16)oc x (4row x 32col) ----------------
// OUTMODE 0: bf16 NHWC (stride 64). 1: bf16 PLANAR [COUT][HW] via omout.p[b].
// 2: f32 NCHW out = lrelu(conv)+res. 3: corr fused -> outf f32.
template<int CIN, bool TWO_IN, bool ACT, bool SCALE, int OUTMODE, int NM>
__global__ __launch_bounds__(256, (CIN == 128 ? 2 : 3)) void conv_mfma(
    const unsigned short* __restrict__ in0, const unsigned short* __restrict__ in1,
    const unsigned short* __restrict__ wgt, const float* __restrict__ bias,
    unsigned short* __restrict__ out, const float* __restrict__ corr,
    const float* __restrict__ res, float* __restrict__ outf,
    Ptr4 omout, int choff, int zdiv, int COUT)
{
    constexpr int H = 180, W = 320, HW = H * W;
    constexpr int NCB = CIN / 8;
    constexpr int NCS = CIN / 32;
    constexpr int NS  = 9 * NCS;
    __shared__ __align__(16) unsigned char lds[6 * 34 * CIN * 2];

    const int tid = threadIdx.x;
    int bx, by, bz;
    swz_decode(bx, by, bz);
    int b, ch;
    if (OUTMODE == 1) { b = bz / zdiv; ch = bz % zdiv + choff; }
    else              { b = bz; ch = 0; }
    const int x0 = bx * 32, y0 = by * 4;

    for (int t = tid; t < 6 * 34 * NCB; t += 256) {
        int cb = t % NCB; int r = t / NCB;
        int xp = r % 34, yp = r / 34;
        int gx = x0 - 1 + xp, gy = y0 - 1 + yp;
        uint4 v = make_uint4(0, 0, 0, 0);
        if (gx >= 0 && gx < W && gy >= 0 && gy < H) {
            size_t pix = (size_t)b * HW + (size_t)gy * W + gx;
            const unsigned short* src;
            if (TWO_IN) src = (cb < 8) ? (in0 + pix * 64 + cb * 8) : (in1 + pix * 64 + (cb - 8) * 8);
            else        src = in0 + pix * CIN + cb * 8;
            v = *(const uint4*)src;
            if (SCALE) {
                float cv = corr[pix];
                v.x = pack2(bflo(v.x) * cv, bfhi(v.x) * cv);
                v.y = pack2(bflo(v.y) * cv, bfhi(v.y) * cv);
                v.z = pack2(bflo(v.z) * cv, bfhi(v.z) * cv);
                v.w = pack2(bflo(v.w) * cv, bfhi(v.w) * cv);
            }
        }
        int blk = cb ^ (xp & 7);
        *(uint4*)&lds[(size_t)((yp * 34 + xp) * NCB + blk) * 16] = v;
    }
    __syncthreads();

    const int wv = tid >> 6, lane = tid & 63;
    const int ll = lane & 15, lh = lane >> 4;
    const unsigned short* wchunk = wgt + (size_t)ch * (9 * NCS * 2048);
    const int alane = ll * 32 + lh * 8;

    f32x4 acc[NM][2];
    #pragma unroll
    for (int mi = 0; mi < NM; ++mi)
        #pragma unroll
        for (int nf = 0; nf < 2; ++nf) acc[mi][nf] = f32x4{0.f, 0.f, 0.f, 0.f};

    // depth-2 rotating register prefetch of A-fragments (weight loads).
    // Static slot indices after full unroll -> registers, no scratch (rule #20).
    short8 abuf[3][NM];
    #pragma unroll
    for (int mi = 0; mi < NM; ++mi) {
        abuf[0][mi] = *(const short8*)(wchunk + (size_t)0 * 2048 + mi * 512 + alane);
        abuf[1][mi] = *(const short8*)(wchunk + (size_t)1 * 2048 + mi * 512 + alane);
    }

    #pragma unroll
    for (int s = 0; s < NS; ++s) {
        if (s + 2 < NS) {
            #pragma unroll
            for (int mi = 0; mi < NM; ++mi)
                abuf[(s + 2) % 3][mi] =
                    *(const short8*)(wchunk + (size_t)(s + 2) * 2048 + mi * 512 + alane);
        }
        const int j = s / NCS, cs = s % NCS;
        const int jy = j / 3, jx = j % 3;
        short8 bf[2];
        #pragma unroll
        for (int nf = 0; nf < 2; ++nf) {
            int xp = nf * 16 + ll + jx;
            int blk = (cs * 4 + lh) ^ (xp & 7);
            int addr = (((wv + jy) * 34 + xp) * NCB + blk) * 16;
            bf[nf] = *(const short8*)&lds[addr];
        }
        #pragma unroll
        for (int mi = 0; mi < NM; ++mi)
            #pragma unroll
            for (int nf = 0; nf < 2; ++nf)
                acc[mi][nf] = __builtin_amdgcn_mfma_f32_16x16x32_bf16(abuf[s % 3][mi], bf[nf], acc[mi][nf], 0, 0, 0);
    }

    const int py = y0 + wv;
    const size_t pixrow = (size_t)b * HW + (size_t)py * W;
    #pragma unroll
    for (int nf = 0; nf < 2; ++nf) {
        const int px = x0 + nf * 16 + ll;
        if (OUTMODE == 3) {
            float dot = 0.f;
            const unsigned* er = (const unsigned*)(in1 + (pixrow + px) * 64);
            #pragma unroll
            for (int mi = 0; mi < NM; ++mi) {
                const int oc_l = mi * 16 + lh * 4;
                unsigned e0 = er[oc_l / 2], e1 = er[oc_l / 2 + 1];
                float t0 = acc[mi][nf][0] + bias[oc_l + 0];
                float t1 = acc[mi][nf][1] + bias[oc_l + 1];
                float t2 = acc[mi][nf][2] + bias[oc_l + 2];
                float t3 = acc[mi][nf][3] + bias[oc_l + 3];
                dot += t0 * bflo(e0) + t1 * bfhi(e0) + t2 * bflo(e1) + t3 * bfhi(e1);
            }
            dot += __shfl_xor(dot, 16);
            dot += __shfl_xor(dot, 32);
            if (lh == 0) outf[pixrow + px] = dot;
        } else if (OUTMODE == 1) {
            unsigned short* oslot = omout.p[b];
            #pragma unroll
            for (int mi = 0; mi < NM; ++mi) {
                const int oc_l = mi * 16 + lh * 4;
                #pragma unroll
                for (int jj = 0; jj < 4; ++jj) {
                    int ocg = ch * 64 + oc_l + jj;
                    if (ocg < COUT) {
                        float t = acc[mi][nf][jj] + bias[ocg];
                        oslot[(size_t)ocg * HW + (size_t)py * W + px] = f2bf(ACT ? lrelu_f(t) : t);
                    }
                }
            }
        } else {
            #pragma unroll
            for (int mi = 0; mi < NM; ++mi) {
                const int oc_l = mi * 16 + lh * 4;
                if (OUTMODE == 0) {
                    float v[4];
                    #pragma unroll
                    for (int jj = 0; jj < 4; ++jj) {
                        float t = acc[mi][nf][jj] + bias[oc_l + jj];
                        v[jj] = ACT ? lrelu_f(t) : t;
                    }
                    uint2 st; st.x = pack2(v[0], v[1]); st.y = pack2(v[2], v[3]);
                    *(uint2*)&out[(pixrow + px) * 64 + oc_l] = st;
                } else {
                    #pragma unroll
                    for (int jj = 0; jj < 4; ++jj) {
                        int oc = oc_l + jj;
                        float t = acc[mi][nf][jj] + bias[oc];
                        if (ACT) t = lrelu_f(t);
                        size_t idx = ((size_t)b * 64 + oc) * HW + (size_t)py * W + px;
                        outf[idx] = t + res[idx];
                    }
                }
            }
        }
    }
}

// ---------------- mdcn v2 (dg=8, Cg=8, 64->64), XCD-swizzled ----------------
template<int ACT>
__global__ __launch_bounds__(256, 4) void mdcn_mfma(
    const unsigned short* __restrict__ x, size_t xstride,
    const unsigned short* __restrict__ om, size_t omstride,
    const unsigned short* __restrict__ wgt, const float* __restrict__ bias,
    unsigned short* __restrict__ out, size_t ostride)
{
    constexpr int H = 180, W = 320, HW = H * W;
    __shared__ __align__(16) unsigned char sv[72 * 32 * 16];

    const int tid = threadIdx.x;
    int bx, by, bz;
    swz_decode(bx, by, bz);
    const unsigned short* xb  = x  + (size_t)bz * xstride;
    const unsigned short* omb = om + (size_t)bz * omstride;
    unsigned short* ob        = out + (size_t)bz * ostride;
    const int px0 = bx * 32;
    const int py  = by;

    {
        const int pxl = tid & 31, g = tid >> 5;
        const int px = px0 + pxl;
        const size_t p = (size_t)py * W + px;
        const unsigned short* omg = omb + (size_t)(g * 9) * HW + p;

        float oyv[9], oxv[9], mmv[9];
        #pragma unroll
        for (int k = 0; k < 9; ++k) oyv[k] = bf2f(omg[(size_t)k * HW]);
        #pragma unroll
        for (int k = 0; k < 9; ++k) oxv[k] = bf2f(omg[(size_t)(72 + k) * HW]);
        #pragma unroll
        for (int k = 0; k < 9; ++k) mmv[k] = bf2f(omg[(size_t)(144 + k) * HW]);

        #pragma unroll
        for (int k = 0; k < 9; ++k) {
            float m = 1.f / (1.f + __expf(-mmv[k]));
            float pyf = (float)(py + (k / 3) - 1) + oyv[k];
            float pxf = (float)(px + (k % 3) - 1) + oxv[k];
            float y0f = floorf(pyf), x0f = floorf(pxf);
            float wy = pyf - y0f, wx = pxf - x0f;
            int yi = (int)y0f, xi = (int)x0f;
            bool vy0 = (yi >= 0) && (yi < H);
            bool vy1 = (yi + 1 >= 0) && (yi + 1 < H);
            bool vx0 = (xi >= 0) && (xi < W);
            bool vx1 = (xi + 1 >= 0) && (xi + 1 < W);
            float w00 = (vy0 && vx0) ? (1.f - wy) * (1.f - wx) * m : 0.f;
            float w01 = (vy0 && vx1) ? (1.f - wy) * wx * m : 0.f;
            float w10 = (vy1 && vx0) ? wy * (1.f - wx) * m : 0.f;
            float w11 = (vy1 && vx1) ? wy * wx * m : 0.f;
            int yc0 = min(max(yi, 0), H - 1), yc1 = min(max(yi + 1, 0), H - 1);
            int xc0 = min(max(xi, 0), W - 1), xc1 = min(max(xi + 1, 0), W - 1);
            uint4 c00 = *(const uint4*)(xb + ((size_t)(yc0 * W + xc0) * 64 + g * 8));
            uint4 c01 = *(const uint4*)(xb + ((size_t)(yc0 * W + xc1) * 64 + g * 8));
            uint4 c10 = *(const uint4*)(xb + ((size_t)(yc1 * W + xc0) * 64 + g * 8));
            uint4 c11 = *(const uint4*)(xb + ((size_t)(yc1 * W + xc1) * 64 + g * 8));
            const unsigned* p00 = (const unsigned*)&c00;
            const unsigned* p01 = (const unsigned*)&c01;
            const unsigned* p10 = (const unsigned*)&c10;
            const unsigned* p11 = (const unsigned*)&c11;
            unsigned r[4];
            #pragma unroll
            for (int q = 0; q < 4; ++q) {
                float lo = w00 * bflo(p00[q]) + w01 * bflo(p01[q]) + w10 * bflo(p10[q]) + w11 * bflo(p11[q]);
                float hi = w00 * bfhi(p00[q]) + w01 * bfhi(p01[q]) + w10 * bfhi(p10[q]) + w11 * bfhi(p11[q]);
                r[q] = pack2(lo, hi);
            }
            *(uint4*)&sv[(size_t)((g * 9 + k) * 32 + pxl) * 16] = *(uint4*)r;
        }
    }
    __syncthreads();

    const int wv = tid >> 6, lane = tid & 63;
    const int ll = lane & 15, lh = lane >> 4;
    f32x4 acc[2] = {f32x4{0.f,0.f,0.f,0.f}, f32x4{0.f,0.f,0.f,0.f}};

    // depth-2 weight prefetch (same rationale as conv_mfma)
    short8 ab[3];
    ab[0] = *(const short8*)(wgt + (size_t)(0 * 64 + wv * 16 + ll) * 32 + lh * 8);
    ab[1] = *(const short8*)(wgt + (size_t)(1 * 64 + wv * 16 + ll) * 32 + lh * 8);
    #pragma unroll
    for (int s = 0; s < 18; ++s) {
        if (s + 2 < 18)
            ab[(s + 2) % 3] = *(const short8*)(wgt + (size_t)((s + 2) * 64 + wv * 16 + ll) * 32 + lh * 8);
        #pragma unroll
        for (int nf = 0; nf < 2; ++nf) {
            short8 bb = *(const short8*)&sv[(size_t)s * 2048 + lh * 512 + (nf * 16 + ll) * 16];
            acc[nf] = __builtin_amdgcn_mfma_f32_16x16x32_bf16(ab[s % 3], bb, acc[nf], 0, 0, 0);
        }
    }
    #pragma unroll
    for (int nf = 0; nf < 2; ++nf) {
        int opx = px0 + nf * 16 + ll;
        int oc0 = wv * 16 + lh * 4;
        float v[4];
        #pragma unroll
        for (int jj = 0; jj < 4; ++jj) {
            float t = acc[nf][jj] + bias[oc0 + jj];
            v[jj] = ACT ? lrelu_f(t) : t;
        }
        uint2 st; st.x = pack2(v[0], v[1]); st.y = pack2(v[2], v[3]);
        *(uint2*)&ob[((size_t)py * W + opx) * 64 + oc0] = st;
    }
}

extern "C" void kernel_launch(void* const* d_in, const int* in_sizes, int n_in,
                              void* d_out, int out_size, void* d_ws, size_t ws_size,
                              hipStream_t stream)
{
    const float* ref    = (const float*)d_in[0];
    const float* neb    = (const float*)d_in[1];
    const float* w_oc1  = (const float*)d_in[2];  const float* b_oc1  = (const float*)d_in[3];
    const float* w_om1  = (const float*)d_in[4];  const float* b_om1  = (const float*)d_in[5];
    const float* w_dcn1 = (const float*)d_in[6];  const float* b_dcn1 = (const float*)d_in[7];
    const float* w_fc   = (const float*)d_in[8];  const float* b_fc   = (const float*)d_in[9];
    const float* w_cas1 = (const float*)d_in[10]; const float* b_cas1 = (const float*)d_in[11];
    const float* w_cas2 = (const float*)d_in[12]; const float* b_cas2 = (const float*)d_in[13];
    const float* w_om2  = (const float*)d_in[14]; const float* b_om2  = (const float*)d_in[15];
    const float* w_dcn2 = (const float*)d_in[16]; const float* b_dcn2 = (const float*)d_in[17];
    const float* w_ta1  = (const float*)d_in[18]; const float* b_ta1  = (const float*)d_in[19];
    const float* w_ta2  = (const float*)d_in[20]; const float* b_ta2  = (const float*)d_in[21];
    const float* w_ff   = (const float*)d_in[22]; const float* b_ff   = (const float*)d_in[23];

    constexpr int H = 180, W = 320, HW = H * W;
    constexpr size_t CHW = (size_t)HW * 64;
    constexpr size_t SLB = 4 * CHW * 2;
    constexpr size_t OMSLOT_EL = (size_t)HW * 216;
    constexpr size_t OMSLOT_B  = OMSLOT_EL * 2;

    char* wsb = (char*)d_ws;
    unsigned short* S0 = (unsigned short*)(wsb);
    unsigned short* S1 = (unsigned short*)(wsb + SLB);
    unsigned short* S2 = (unsigned short*)(wsb + 2 * SLB);
    unsigned short* S3 = (unsigned short*)(wsb + 3 * SLB);
    float* corrf = (float*)S3;
    unsigned short* ffw = (unsigned short*)(wsb + SLB + (2u << 20));

    char* doutb = (char*)d_out;
    unsigned short* omA0 = (unsigned short*)doutb;
    unsigned short* omA1 = omA0 + OMSLOT_EL;
    unsigned short* wb   = (unsigned short*)(doutb + 2 * OMSLOT_B);
    const bool big = ws_size >= 4 * SLB + 2 * OMSLOT_B;
    unsigned short* omB0 = (unsigned short*)(wsb + 4 * SLB);
    unsigned short* omB1 = omB0 + OMSLOT_EL;

    unsigned short* w_oc1p = wb + 0;
    unsigned short* w_om1p = wb + 73728;
    unsigned short* w_dcn1p= wb + 221184;
    unsigned short* w_fcp  = wb + 258048;
    unsigned short* w_cas1p= wb + 294912;
    unsigned short* w_cas2p= wb + 368640;
    unsigned short* w_om2p = wb + 405504;
    unsigned short* w_dcn2p= wb + 552960;
    unsigned short* w_ta1p = wb + 589824;
    unsigned short* w_ta2p = wb + 626688;
    unsigned short* w_ffp  = wb + 663552;

    dim3 blk(256);
    dim3 g4(10, 45, 4);
    dim3 gm(10, 180, 2);
    Ptr4 none{};

    nchw2nhwc2<<<1800, blk, 0, stream>>>(ref, neb, S0, S1);

    {
        PrepArgs pa;
        const float* srcs[11] = {w_oc1, w_om1, w_dcn1, w_fc, w_cas1, w_cas2, w_om2, w_dcn2, w_ta1, w_ta2, w_ff};
        unsigned short* dsts[11] = {w_oc1p, w_om1p, w_dcn1p, w_fcp, w_cas1p, w_cas2p, w_om2p, w_dcn2p, w_ta1p, w_ta2p, w_ffp};
        int couts[11] = {64, 216, 0, 64, 64, 64, 216, 0, 64, 64, 64};
        int cins[11]  = {128, 64, 0, 64, 128, 64, 64, 0, 64, 64, 64};
        int nchs[11]  = {1, 4, 0, 1, 1, 1, 4, 0, 1, 1, 1};
        int kinds[11] = {0, 0, 1, 0, 0, 0, 0, 1, 0, 0, 0};
        for (int i = 0; i < 11; ++i) {
            pa.src[i] = srcs[i]; pa.dst[i] = dsts[i];
            pa.cout[i] = couts[i]; pa.cin[i] = cins[i]; pa.nch[i] = nchs[i]; pa.kind[i] = kinds[i];
        }
        prep_all<<<dim3(576, 11), blk, 0, stream>>>(pa);
    }

    // 1. off1 = lrelu(conv(concat(neb,ref))) -> S2
    conv_mfma<128, true, true, false, 0, 4><<<g4, blk, 0, stream>>>(
        S1, S0, w_oc1p, b_oc1, S2, nullptr, nullptr, nullptr, none, 0, 1, 64);

    // om conv: chunks 0-2 (NM=4) + chunk 3 tail (NM=2)
    auto ompack = [&](const unsigned short* inp, const unsigned short* wp, const float* bp,
                      Ptr4 slots, int nb){
        conv_mfma<64, false, false, false, 1, 4><<<dim3(10, 45, 3 * nb), blk, 0, stream>>>(
            inp, nullptr, wp, bp, nullptr, nullptr, nullptr, nullptr, slots, 0, 3, 216);
        conv_mfma<64, false, false, false, 1, 2><<<dim3(10, 45, nb), blk, 0, stream>>>(
            inp, nullptr, wp, bp, nullptr, nullptr, nullptr, nullptr, slots, 3, 1, 216);
    };

    // 2. pack1: om1 = conv(off1) [planar]; feat1 = mdcn(neb_t, om1) -> S3
    if (big) {
        Ptr4 slots{omA0, omA1, omB0, omB1};
        ompack(S2, w_om1p, b_om1, slots, 4);
        mdcn_mfma<0><<<gm, blk, 0, stream>>>(S1, CHW, omA0, OMSLOT_EL, w_dcn1p, b_dcn1, S3, CHW);
        mdcn_mfma<0><<<gm, blk, 0, stream>>>(S1 + 2 * CHW, CHW, omB0, OMSLOT_EL, w_dcn1p, b_dcn1, S3 + 2 * CHW, CHW);
    } else {
        Ptr4 slots{omA0, omA1, nullptr, nullptr};
        for (int pp = 0; pp < 2; ++pp) {
            ompack(S2 + 2 * pp * CHW, w_om1p, b_om1, slots, 2);
            mdcn_mfma<0><<<gm, blk, 0, stream>>>(S1 + 2 * pp * CHW, CHW, omA0, OMSLOT_EL,
                                                 w_dcn1p, b_dcn1, S3 + 2 * pp * CHW, CHW);
        }
    }

    // 3. feat2 = lrelu(conv(feat1)) -> S2
    conv_mfma<64, false, true, false, 0, 4><<<g4, blk, 0, stream>>>(
        S3, nullptr, w_fcp, b_fc, S2, nullptr, nullptr, nullptr, none, 0, 1, 64);
    // 4. cas_a = lrelu(conv(concat(feat2,ref))) -> S1
    conv_mfma<128, true, true, false, 0, 4><<<g4, blk, 0, stream>>>(
        S2, S0, w_cas1p, b_cas1, S1, nullptr, nullptr, nullptr, none, 0, 1, 64);
    // 5. off2 = lrelu(conv(cas_a)) -> S3
    conv_mfma<64, false, true, false, 0, 4><<<g4, blk, 0, stream>>>(
        S1, nullptr, w_cas2p, b_cas2, S3, nullptr, nullptr, nullptr, none, 0, 1, 64);

    // 6. pack2: om2 = conv(off2); feat3 = lrelu(mdcn(feat2, om2)) -> S1
    if (big) {
        Ptr4 slots{omA0, omA1, omB0, omB1};
        ompack(S3, w_om2p, b_om2, slots, 4);
        mdcn_mfma<1><<<gm, blk, 0, stream>>>(S2, CHW, omA0, OMSLOT_EL, w_dcn2p, b_dcn2, S1, CHW);
        mdcn_mfma<1><<<gm, blk, 0, stream>>>(S2 + 2 * CHW, CHW, omB0, OMSLOT_EL, w_dcn2p, b_dcn2, S1 + 2 * CHW, CHW);
    } else {
        Ptr4 slots{omA0, omA1, nullptr, nullptr};
        for (int pp = 0; pp < 2; ++pp) {
            ompack(S3 + 2 * pp * CHW, w_om2p, b_om2, slots, 2);
            mdcn_mfma<1><<<gm, blk, 0, stream>>>(S2 + 2 * pp * CHW, CHW, omA0, OMSLOT_EL,
                                                 w_dcn2p, b_dcn2, S1 + 2 * pp * CHW, CHW);
        }
    }

    // 7. emb_ref = conv(ref_t, ta1) -> S2 ; corr = dot(conv(feat3, ta2), emb_ref) (fused)
    conv_mfma<64, false, false, false, 0, 4><<<g4, blk, 0, stream>>>(
        S0, nullptr, w_ta1p, b_ta1, S2, nullptr, nullptr, nullptr, none, 0, 1, 64);
    conv_mfma<64, false, false, false, 3, 4><<<g4, blk, 0, stream>>>(
        S1, S2, w_ta2p, b_ta2, nullptr, nullptr, nullptr, corrf, none, 0, 1, 64);

    // relocate ff weights out of d_out before the final conv overwrites it
    hipMemcpyAsync(ffw, w_ffp, 36864 * 2, hipMemcpyDeviceToDevice, stream);

    // 8. out = lrelu(conv(ref_t*corr, ff)) + ref  (f32 NCHW into d_out)
    conv_mfma<64, false, true, true, 2, 4><<<g4, blk, 0, stream>>>(
        S0, nullptr, ffw, b_ff, nullptr, corrf, ref, (float*)d_out, none, 0, 1, 64);
}

// Round 9
// 1156.940 us; speedup vs baseline: 2.8943x; 1.0076x over previous
//
#include <hip/hip_runtime.h>
#include <cmath>

// fusion_36455682409119 round 9:
//  - conv_mfma gains NF (x-frags) template param: CIN=64 convs use NF=4 (64px
//    tiles, 288 MFMA/wave per staged halo, 2x A-load reuse, LDS 50.7KB 3blk/CU)
//  - NEW tacorr_mfma: ta1+ta2+corr fused (dual halo, both accs in regs, dot
//    in-register) -> kills 1 dispatch + 30MB emb_ref round-trip
//  - mdcn: paired launches merged to one z=4 dispatch via Ptr4 om table
//  - r8 lesson: no source-level scheduling tricks (compiler folds them)

using short8 = __attribute__((ext_vector_type(8))) short;
using f32x4  = __attribute__((ext_vector_type(4))) float;

#define DEVINL static __device__ __forceinline__

DEVINL unsigned short f2bf(float f){
    unsigned u = __float_as_uint(f);
    u += 0x7fffu + ((u >> 16) & 1u);
    return (unsigned short)(u >> 16);
}
DEVINL unsigned pack2(float a, float b){ return (unsigned)f2bf(a) | ((unsigned)f2bf(b) << 16); }
DEVINL float bflo(unsigned u){ return __uint_as_float(u << 16); }
DEVINL float bfhi(unsigned u){ return __uint_as_float(u & 0xffff0000u); }
DEVINL float bf2f(unsigned short u){ return __uint_as_float((unsigned)u << 16); }
DEVINL float lrelu_f(float v){ return v >= 0.f ? v : 0.1f * v; }

// m204 bijective XCD swizzle
DEVINL void swz_decode(int& bx, int& by, int& bz){
    const int gx = gridDim.x, gy = gridDim.y;
    int lin = blockIdx.x + gx * (blockIdx.y + gy * blockIdx.z);
    int nwg = gx * gy * gridDim.z;
    int q = nwg >> 3, r = nwg & 7;
    int xcd = lin & 7, idx = lin >> 3;
    int swz = (xcd < r ? xcd * (q + 1) : r + xcd * q) + idx;
    bz = swz / (gx * gy);
    int rem = swz - bz * gx * gy;
    by = rem / gx; bx = rem - by * gx;
}

struct Ptr4 { unsigned short* p[4]; };

// ---------------- both NCHW f32 -> NHWC bf16 transposes in one launch ----------------
__global__ __launch_bounds__(256) void nchw2nhwc2(const float* __restrict__ inA,
                                                  const float* __restrict__ inB,
                                                  unsigned short* __restrict__ outA,
                                                  unsigned short* __restrict__ outB)
{
    constexpr int HW = 180 * 320;
    const int blk = blockIdx.x;
    const float* in = (blk < 900) ? inA : inB;
    unsigned short* out = (blk < 900) ? outA : outB;
    size_t idx = (size_t)(blk % 900) * 256 + threadIdx.x;
    size_t bb = idx / HW, p = idx % HW;
    const float* src = in + (bb * 64) * (size_t)HW + p;
    unsigned short* dst = out + idx * 64;
    #pragma unroll
    for (int c0 = 0; c0 < 64; c0 += 16) {
        unsigned r[8];
        #pragma unroll
        for (int q = 0; q < 8; ++q)
            r[q] = pack2(src[(size_t)(c0 + 2*q) * HW], src[(size_t)(c0 + 2*q + 1) * HW]);
        *(uint4*)(dst + c0)     = *(uint4*)&r[0];
        *(uint4*)(dst + c0 + 8) = *(uint4*)&r[4];
    }
}

// ---------------- all weight prepacks in one launch ----------------
struct PrepArgs {
    const float* src[11];
    unsigned short* dst[11];
    int cout[11]; int cin[11]; int nch[11]; int kind[11];
};

__global__ __launch_bounds__(256) void prep_all(PrepArgs a)
{
    const int t = blockIdx.y;
    const int idx = blockIdx.x * 256 + threadIdx.x;
    if (a.kind[t] == 1) {
        if (idx >= 36864) return;
        int kk = idx & 31, oc = (idx >> 5) & 63, s = idx >> 11;
        int k = s * 32 + kk;
        int gt = k >> 3, c8 = k & 7;
        int g = gt / 9, tp = gt - g * 9;
        a.dst[t][idx] = f2bf(a.src[t][((size_t)oc * 64 + g * 8 + c8) * 9 + tp]);
    } else {
        int cin = a.cin[t], cout = a.cout[t];
        int ncs = cin / 32;
        int total = a.nch[t] * 9 * ncs * 2048;
        if (idx >= total) return;
        int kk = idx & 31, oc_l = (idx >> 5) & 63, rest = idx >> 11;
        int cs = rest % ncs; int rest2 = rest / ncs;
        int j = rest2 % 9; int ch = rest2 / 9;
        int oc = ch * 64 + oc_l, c = cs * 32 + kk;
        float v = (oc < cout) ? a.src[t][((size_t)oc * cin + c) * 9 + j] : 0.f;
        a.dst[t][idx] = f2bf(v);
    }
}

// ---------------- MFMA conv 3x3 SAME, tile (NM*16)oc x (4row x NF*16 px) ----------------
// OUTMODE 0: bf16 NHWC (stride 64). 1: bf16 PLANAR [COUT][HW] via omout.p[b].
// 2: f32 NCHW out = lrelu(conv)+res.
template<int CIN, bool TWO_IN, bool ACT, bool SCALE, int OUTMODE, int NM, int NF>
__global__ __launch_bounds__(256, (CIN == 128 ? 2 : 3)) void conv_mfma(
    const unsigned short* __restrict__ in0, const unsigned short* __restrict__ in1,
    const unsigned short* __restrict__ wgt, const float* __restrict__ bias,
    unsigned short* __restrict__ out, const float* __restrict__ corr,
    const float* __restrict__ res, float* __restrict__ outf,
    Ptr4 omout, int choff, int zdiv, int COUT)
{
    constexpr int H = 180, W = 320, HW = H * W;
    constexpr int NCB = CIN / 8;
    constexpr int NCS = CIN / 32;
    constexpr int XW  = NF * 16 + 2;
    __shared__ __align__(16) unsigned char lds[6 * XW * CIN * 2];

    const int tid = threadIdx.x;
    int bx, by, bz;
    swz_decode(bx, by, bz);
    int b, ch;
    if (OUTMODE == 1) { b = bz / zdiv; ch = bz % zdiv + choff; }
    else              { b = bz; ch = 0; }
    const int x0 = bx * (NF * 16), y0 = by * 4;

    for (int t = tid; t < 6 * XW * NCB; t += 256) {
        int cb = t % NCB; int r = t / NCB;
        int xp = r % XW, yp = r / XW;
        int gx = x0 - 1 + xp, gy = y0 - 1 + yp;
        uint4 v = make_uint4(0, 0, 0, 0);
        if (gx >= 0 && gx < W && gy >= 0 && gy < H) {
            size_t pix = (size_t)b * HW + (size_t)gy * W + gx;
            const unsigned short* src;
            if (TWO_IN) src = (cb < 8) ? (in0 + pix * 64 + cb * 8) : (in1 + pix * 64 + (cb - 8) * 8);
            else        src = in0 + pix * CIN + cb * 8;
            v = *(const uint4*)src;
            if (SCALE) {
                float cv = corr[pix];
                v.x = pack2(bflo(v.x) * cv, bfhi(v.x) * cv);
                v.y = pack2(bflo(v.y) * cv, bfhi(v.y) * cv);
                v.z = pack2(bflo(v.z) * cv, bfhi(v.z) * cv);
                v.w = pack2(bflo(v.w) * cv, bfhi(v.w) * cv);
            }
        }
        int blk = cb ^ (xp & 7);
        *(uint4*)&lds[(size_t)((yp * XW + xp) * NCB + blk) * 16] = v;
    }
    __syncthreads();

    const int wv = tid >> 6, lane = tid & 63;
    const int ll = lane & 15, lh = lane >> 4;
    const unsigned short* wchunk = wgt + (size_t)ch * (9 * NCS * 2048);
    const int alane = ll * 32 + lh * 8;

    f32x4 acc[NM][NF];
    #pragma unroll
    for (int mi = 0; mi < NM; ++mi)
        #pragma unroll
        for (int nf = 0; nf < NF; ++nf) acc[mi][nf] = f32x4{0.f, 0.f, 0.f, 0.f};

    #pragma unroll
    for (int j = 0; j < 9; ++j) {
        const int jy = j / 3, jx = j % 3;
        #pragma unroll
        for (int cs = 0; cs < NCS; ++cs) {
            const int s = j * NCS + cs;
            short8 a[NM];
            #pragma unroll
            for (int mi = 0; mi < NM; ++mi)
                a[mi] = *(const short8*)(wchunk + (size_t)s * 2048 + mi * 512 + alane);
            short8 bf[NF];
            #pragma unroll
            for (int nf = 0; nf < NF; ++nf) {
                int xp = nf * 16 + ll + jx;
                int blk = (cs * 4 + lh) ^ (xp & 7);
                int addr = (((wv + jy) * XW + xp) * NCB + blk) * 16;
                bf[nf] = *(const short8*)&lds[addr];
            }
            #pragma unroll
            for (int mi = 0; mi < NM; ++mi)
                #pragma unroll
                for (int nf = 0; nf < NF; ++nf)
                    acc[mi][nf] = __builtin_amdgcn_mfma_f32_16x16x32_bf16(a[mi], bf[nf], acc[mi][nf], 0, 0, 0);
        }
    }

    const int py = y0 + wv;
    const size_t pixrow = (size_t)b * HW + (size_t)py * W;
    #pragma unroll
    for (int nf = 0; nf < NF; ++nf) {
        const int px = x0 + nf * 16 + ll;
        if (OUTMODE == 1) {
            unsigned short* oslot = omout.p[b];
            #pragma unroll
            for (int mi = 0; mi < NM; ++mi) {
                const int oc_l = mi * 16 + lh * 4;
                #pragma unroll
                for (int jj = 0; jj < 4; ++jj) {
                    int ocg = ch * 64 + oc_l + jj;
                    if (ocg < COUT) {
                        float t = acc[mi][nf][jj] + bias[ocg];
                        oslot[(size_t)ocg * HW + (size_t)py * W + px] = f2bf(ACT ? lrelu_f(t) : t);
                    }
                }
            }
        } else {
            #pragma unroll
            for (int mi = 0; mi < NM; ++mi) {
                const int oc_l = mi * 16 + lh * 4;
                if (OUTMODE == 0) {
                    float v[4];
                    #pragma unroll
                    for (int jj = 0; jj < 4; ++jj) {
                        float t = acc[mi][nf][jj] + bias[oc_l + jj];
                        v[jj] = ACT ? lrelu_f(t) : t;
                    }
                    uint2 st; st.x = pack2(v[0], v[1]); st.y = pack2(v[2], v[3]);
                    *(uint2*)&out[(pixrow + px) * 64 + oc_l] = st;
                } else {
                    #pragma unroll
                    for (int jj = 0; jj < 4; ++jj) {
                        int oc = oc_l + jj;
                        float t = acc[mi][nf][jj] + bias[oc];
                        if (ACT) t = lrelu_f(t);
                        size_t idx = ((size_t)b * 64 + oc) * HW + (size_t)py * W + px;
                        outf[idx] = t + res[idx];
                    }
                }
            }
        }
    }
}

// ---------------- fused ta1+ta2+corr: dual 64-ch halo, two convs in regs, dot ----------------
__global__ __launch_bounds__(256, 3) void tacorr_mfma(
    const unsigned short* __restrict__ inR,   // ref_t (ta1 input)
    const unsigned short* __restrict__ inE,   // feat3 (ta2 input)
    const unsigned short* __restrict__ wR, const float* __restrict__ bR,
    const unsigned short* __restrict__ wE, const float* __restrict__ bE,
    float* __restrict__ outf)
{
    constexpr int H = 180, W = 320, HW = H * W;
    constexpr int NE1 = 6 * 34 * 8;   // elements per halo
    __shared__ __align__(16) unsigned char lds[2][6 * 34 * 64 * 2];

    const int tid = threadIdx.x;
    int bx, by, bz;
    swz_decode(bx, by, bz);
    const int b = bz;
    const int x0 = bx * 32, y0 = by * 4;

    for (int t = tid; t < 2 * NE1; t += 256) {
        int half = t / NE1, e = t - half * NE1;
        int cb = e & 7; int r = e >> 3;
        int xp = r % 34, yp = r / 34;
        int gx = x0 - 1 + xp, gy = y0 - 1 + yp;
        uint4 v = make_uint4(0, 0, 0, 0);
        if (gx >= 0 && gx < W && gy >= 0 && gy < H) {
            size_t pix = (size_t)b * HW + (size_t)gy * W + gx;
            const unsigned short* src = (half ? inE : inR) + pix * 64 + cb * 8;
            v = *(const uint4*)src;
        }
        int blk = cb ^ (xp & 7);
        *(uint4*)&lds[half][(size_t)((yp * 34 + xp) * 8 + blk) * 16] = v;
    }
    __syncthreads();

    const int wv = tid >> 6, lane = tid & 63;
    const int ll = lane & 15, lh = lane >> 4;
    const int alane = ll * 32 + lh * 8;

    f32x4 accR[4][2], accE[4][2];
    #pragma unroll
    for (int mi = 0; mi < 4; ++mi)
        #pragma unroll
        for (int nf = 0; nf < 2; ++nf) { accR[mi][nf] = f32x4{0,0,0,0}; accE[mi][nf] = f32x4{0,0,0,0}; }

    #pragma unroll
    for (int j = 0; j < 9; ++j) {
        const int jy = j / 3, jx = j % 3;
        #pragma unroll
        for (int cs = 0; cs < 2; ++cs) {
            const int s = j * 2 + cs;
            short8 aR[4], aE[4];
            #pragma unroll
            for (int mi = 0; mi < 4; ++mi) {
                aR[mi] = *(const short8*)(wR + (size_t)s * 2048 + mi * 512 + alane);
                aE[mi] = *(const short8*)(wE + (size_t)s * 2048 + mi * 512 + alane);
            }
            #pragma unroll
            for (int nf = 0; nf < 2; ++nf) {
                int xp = nf * 16 + ll + jx;
                int blk = (cs * 4 + lh) ^ (xp & 7);
                int addr = (((wv + jy) * 34 + xp) * 8 + blk) * 16;
                short8 bfR = *(const short8*)&lds[0][addr];
                short8 bfE = *(const short8*)&lds[1][addr];
                #pragma unroll
                for (int mi = 0; mi < 4; ++mi) {
                    accR[mi][nf] = __builtin_amdgcn_mfma_f32_16x16x32_bf16(aR[mi], bfR, accR[mi][nf], 0, 0, 0);
                    accE[mi][nf] = __builtin_amdgcn_mfma_f32_16x16x32_bf16(aE[mi], bfE, accE[mi][nf], 0, 0, 0);
                }
            }
        }
    }

    const int py = y0 + wv;
    const size_t pixrow = (size_t)b * HW + (size_t)py * W;
    #pragma unroll
    for (int nf = 0; nf < 2; ++nf) {
        const int px = x0 + nf * 16 + ll;
        float dot = 0.f;
        #pragma unroll
        for (int mi = 0; mi < 4; ++mi) {
            const int oc_l = mi * 16 + lh * 4;
            #pragma unroll
            for (int jj = 0; jj < 4; ++jj)
                dot += (accR[mi][nf][jj] + bR[oc_l + jj]) * (accE[mi][nf][jj] + bE[oc_l + jj]);
        }
        dot += __shfl_xor(dot, 16);
        dot += __shfl_xor(dot, 32);
        if (lh == 0) outf[pixrow + px] = dot;
    }
}

// ---------------- mdcn v2 (dg=8, Cg=8, 64->64), XCD-swizzled, z = batches ----------------
template<int ACT>
__global__ __launch_bounds__(256, 4) void mdcn_mfma(
    const unsigned short* __restrict__ x, Ptr4 omslots,
    const unsigned short* __restrict__ wgt, const float* __restrict__ bias,
    unsigned short* __restrict__ out)
{
    constexpr int H = 180, W = 320, HW = H * W;
    constexpr size_t CHW = (size_t)HW * 64;
    __shared__ __align__(16) unsigned char sv[72 * 32 * 16];

    const int tid = threadIdx.x;
    int bx, by, bz;
    swz_decode(bx, by, bz);
    const unsigned short* xb  = x + (size_t)bz * CHW;
    const unsigned short* omb = omslots.p[bz];
    unsigned short* ob        = out + (size_t)bz * CHW;
    const int px0 = bx * 32;
    const int py  = by;

    {
        const int pxl = tid & 31, g = tid >> 5;
        const int px = px0 + pxl;
        const size_t p = (size_t)py * W + px;
        const unsigned short* omg = omb + (size_t)(g * 9) * HW + p;

        float oyv[9], oxv[9], mmv[9];
        #pragma unroll
        for (int k = 0; k < 9; ++k) oyv[k] = bf2f(omg[(size_t)k * HW]);
        #pragma unroll
        for (int k = 0; k < 9; ++k) oxv[k] = bf2f(omg[(size_t)(72 + k) * HW]);
        #pragma unroll
        for (int k = 0; k < 9; ++k) mmv[k] = bf2f(omg[(size_t)(144 + k) * HW]);

        #pragma unroll
        for (int k = 0; k < 9; ++k) {
            float m = 1.f / (1.f + __expf(-mmv[k]));
            float pyf = (float)(py + (k / 3) - 1) + oyv[k];
            float pxf = (float)(px + (k % 3) - 1) + oxv[k];
            float y0f = floorf(pyf), x0f = floorf(pxf);
            float wy = pyf - y0f, wx = pxf - x0f;
            int yi = (int)y0f, xi = (int)x0f;
            bool vy0 = (yi >= 0) && (yi < H);
            bool vy1 = (yi + 1 >= 0) && (yi + 1 < H);
            bool vx0 = (xi >= 0) && (xi < W);
            bool vx1 = (xi + 1 >= 0) && (xi + 1 < W);
            float w00 = (vy0 && vx0) ? (1.f - wy) * (1.f - wx) * m : 0.f;
            float w01 = (vy0 && vx1) ? (1.f - wy) * wx * m : 0.f;
            float w10 = (vy1 && vx0) ? wy * (1.f - wx) * m : 0.f;
            float w11 = (vy1 && vx1) ? wy * wx * m : 0.f;
            int yc0 = min(max(yi, 0), H - 1), yc1 = min(max(yi + 1, 0), H - 1);
            int xc0 = min(max(xi, 0), W - 1), xc1 = min(max(xi + 1, 0), W - 1);
            uint4 c00 = *(const uint4*)(xb + ((size_t)(yc0 * W + xc0) * 64 + g * 8));
            uint4 c01 = *(const uint4*)(xb + ((size_t)(yc0 * W + xc1) * 64 + g * 8));
            uint4 c10 = *(const uint4*)(xb + ((size_t)(yc1 * W + xc0) * 64 + g * 8));
            uint4 c11 = *(const uint4*)(xb + ((size_t)(yc1 * W + xc1) * 64 + g * 8));
            const unsigned* p00 = (const unsigned*)&c00;
            const unsigned* p01 = (const unsigned*)&c01;
            const unsigned* p10 = (const unsigned*)&c10;
            const unsigned* p11 = (const unsigned*)&c11;
            unsigned r[4];
            #pragma unroll
            for (int q = 0; q < 4; ++q) {
                float lo = w00 * bflo(p00[q]) + w01 * bflo(p01[q]) + w10 * bflo(p10[q]) + w11 * bflo(p11[q]);
                float hi = w00 * bfhi(p00[q]) + w01 * bfhi(p01[q]) + w10 * bfhi(p10[q]) + w11 * bfhi(p11[q]);
                r[q] = pack2(lo, hi);
            }
            *(uint4*)&sv[(size_t)((g * 9 + k) * 32 + pxl) * 16] = *(uint4*)r;
        }
    }
    __syncthreads();

    const int wv = tid >> 6, lane = tid & 63;
    const int ll = lane & 15, lh = lane >> 4;
    f32x4 acc[2] = {f32x4{0.f,0.f,0.f,0.f}, f32x4{0.f,0.f,0.f,0.f}};
    #pragma unroll
    for (int s = 0; s < 18; ++s) {
        short8 a = *(const short8*)(wgt + (size_t)(s * 64 + wv * 16 + ll) * 32 + lh * 8);
        #pragma unroll
        for (int nf = 0; nf < 2; ++nf) {
            short8 bb = *(const short8*)&sv[(size_t)s * 2048 + lh * 512 + (nf * 16 + ll) * 16];
            acc[nf] = __builtin_amdgcn_mfma_f32_16x16x32_bf16(a, bb, acc[nf], 0, 0, 0);
        }
    }
    #pragma unroll
    for (int nf = 0; nf < 2; ++nf) {
        int opx = px0 + nf * 16 + ll;
        int oc0 = wv * 16 + lh * 4;
        float v[4];
        #pragma unroll
        for (int jj = 0; jj < 4; ++jj) {
            float t = acc[nf][jj] + bias[oc0 + jj];
            v[jj] = ACT ? lrelu_f(t) : t;
        }
        uint2 st; st.x = pack2(v[0], v[1]); st.y = pack2(v[2], v[3]);
        *(uint2*)&ob[((size_t)py * W + opx) * 64 + oc0] = st;
    }
}

extern "C" void kernel_launch(void* const* d_in, const int* in_sizes, int n_in,
                              void* d_out, int out_size, void* d_ws, size_t ws_size,
                              hipStream_t stream)
{
    const float* ref    = (const float*)d_in[0];
    const float* neb    = (const float*)d_in[1];
    const float* w_oc1  = (const float*)d_in[2];  const float* b_oc1  = (const float*)d_in[3];
    const float* w_om1  = (const float*)d_in[4];  const float* b_om1  = (const float*)d_in[5];
    const float* w_dcn1 = (const float*)d_in[6];  const float* b_dcn1 = (const float*)d_in[7];
    const float* w_fc   = (const float*)d_in[8];  const float* b_fc   = (const float*)d_in[9];
    const float* w_cas1 = (const float*)d_in[10]; const float* b_cas1 = (const float*)d_in[11];
    const float* w_cas2 = (const float*)d_in[12]; const float* b_cas2 = (const float*)d_in[13];
    const float* w_om2  = (const float*)d_in[14]; const float* b_om2  = (const float*)d_in[15];
    const float* w_dcn2 = (const float*)d_in[16]; const float* b_dcn2 = (const float*)d_in[17];
    const float* w_ta1  = (const float*)d_in[18]; const float* b_ta1  = (const float*)d_in[19];
    const float* w_ta2  = (const float*)d_in[20]; const float* b_ta2  = (const float*)d_in[21];
    const float* w_ff   = (const float*)d_in[22]; const float* b_ff   = (const float*)d_in[23];

    constexpr int H = 180, W = 320, HW = H * W;
    constexpr size_t CHW = (size_t)HW * 64;
    constexpr size_t SLB = 4 * CHW * 2;
    constexpr size_t OMSLOT_EL = (size_t)HW * 216;
    constexpr size_t OMSLOT_B  = OMSLOT_EL * 2;

    char* wsb = (char*)d_ws;
    unsigned short* S0 = (unsigned short*)(wsb);
    unsigned short* S1 = (unsigned short*)(wsb + SLB);
    unsigned short* S2 = (unsigned short*)(wsb + 2 * SLB);
    unsigned short* S3 = (unsigned short*)(wsb + 3 * SLB);
    float* corrf = (float*)S3;
    unsigned short* ffw = (unsigned short*)(wsb + SLB + (2u << 20));

    char* doutb = (char*)d_out;
    unsigned short* omA0 = (unsigned short*)doutb;
    unsigned short* omA1 = omA0 + OMSLOT_EL;
    unsigned short* wb   = (unsigned short*)(doutb + 2 * OMSLOT_B);
    const bool big = ws_size >= 4 * SLB + 2 * OMSLOT_B;
    unsigned short* omB0 = (unsigned short*)(wsb + 4 * SLB);
    unsigned short* omB1 = omB0 + OMSLOT_EL;

    unsigned short* w_oc1p = wb + 0;
    unsigned short* w_om1p = wb + 73728;
    unsigned short* w_dcn1p= wb + 221184;
    unsigned short* w_fcp  = wb + 258048;
    unsigned short* w_cas1p= wb + 294912;
    unsigned short* w_cas2p= wb + 368640;
    unsigned short* w_om2p = wb + 405504;
    unsigned short* w_dcn2p= wb + 552960;
    unsigned short* w_ta1p = wb + 589824;
    unsigned short* w_ta2p = wb + 626688;
    unsigned short* w_ffp  = wb + 663552;

    dim3 blk(256);
    dim3 g4(10, 45, 4);       // CIN=128 (NF=2) grid
    dim3 g4w(5, 45, 4);       // CIN=64 NF=4 grid
    Ptr4 none{};

    nchw2nhwc2<<<1800, blk, 0, stream>>>(ref, neb, S0, S1);

    {
        PrepArgs pa;
        const float* srcs[11] = {w_oc1, w_om1, w_dcn1, w_fc, w_cas1, w_cas2, w_om2, w_dcn2, w_ta1, w_ta2, w_ff};
        unsigned short* dsts[11] = {w_oc1p, w_om1p, w_dcn1p, w_fcp, w_cas1p, w_cas2p, w_om2p, w_dcn2p, w_ta1p, w_ta2p, w_ffp};
        int couts[11] = {64, 216, 0, 64, 64, 64, 216, 0, 64, 64, 64};
        int cins[11]  = {128, 64, 0, 64, 128, 64, 64, 0, 64, 64, 64};
        int nchs[11]  = {1, 4, 0, 1, 1, 1, 4, 0, 1, 1, 1};
        int kinds[11] = {0, 0, 1, 0, 0, 0, 0, 1, 0, 0, 0};
        for (int i = 0; i < 11; ++i) {
            pa.src[i] = srcs[i]; pa.dst[i] = dsts[i];
            pa.cout[i] = couts[i]; pa.cin[i] = cins[i]; pa.nch[i] = nchs[i]; pa.kind[i] = kinds[i];
        }
        prep_all<<<dim3(576, 11), blk, 0, stream>>>(pa);
    }

    // 1. off1 = lrelu(conv(concat(neb,ref))) -> S2
    conv_mfma<128, true, true, false, 0, 4, 2><<<g4, blk, 0, stream>>>(
        S1, S0, w_oc1p, b_oc1, S2, nullptr, nullptr, nullptr, none, 0, 1, 64);

    // om conv: chunks 0-2 (NM=4) + chunk 3 tail (NM=2), both NF=4
    auto ompack = [&](const unsigned short* inp, const unsigned short* wp, const float* bp,
                      Ptr4 slots, int nb){
        conv_mfma<64, false, false, false, 1, 4, 4><<<dim3(5, 45, 3 * nb), blk, 0, stream>>>(
            inp, nullptr, wp, bp, nullptr, nullptr, nullptr, nullptr, slots, 0, 3, 216);
        conv_mfma<64, false, false, false, 1, 2, 4><<<dim3(5, 45, nb), blk, 0, stream>>>(
            inp, nullptr, wp, bp, nullptr, nullptr, nullptr, nullptr, slots, 3, 1, 216);
    };

    // 2. pack1: om1 = conv(off1) [planar]; feat1 = mdcn(neb_t, om1) -> S3
    if (big) {
        Ptr4 slots{omA0, omA1, omB0, omB1};
        ompack(S2, w_om1p, b_om1, slots, 4);
        mdcn_mfma<0><<<dim3(10, 180, 4), blk, 0, stream>>>(S1, slots, w_dcn1p, b_dcn1, S3);
    } else {
        Ptr4 slots{omA0, omA1, nullptr, nullptr};
        for (int pp = 0; pp < 2; ++pp) {
            ompack(S2 + 2 * pp * CHW, w_om1p, b_om1, slots, 2);
            mdcn_mfma<0><<<dim3(10, 180, 2), blk, 0, stream>>>(S1 + 2 * pp * CHW, slots,
                                                               w_dcn1p, b_dcn1, S3 + 2 * pp * CHW);
        }
    }

    // 3. feat2 = lrelu(conv(feat1)) -> S2
    conv_mfma<64, false, true, false, 0, 4, 4><<<g4w, blk, 0, stream>>>(
        S3, nullptr, w_fcp, b_fc, S2, nullptr, nullptr, nullptr, none, 0, 1, 64);
    // 4. cas_a = lrelu(conv(concat(feat2,ref))) -> S1
    conv_mfma<128, true, true, false, 0, 4, 2><<<g4, blk, 0, stream>>>(
        S2, S0, w_cas1p, b_cas1, S1, nullptr, nullptr, nullptr, none, 0, 1, 64);
    // 5. off2 = lrelu(conv(cas_a)) -> S3
    conv_mfma<64, false, true, false, 0, 4, 4><<<g4w, blk, 0, stream>>>(
        S1, nullptr, w_cas2p, b_cas2, S3, nullptr, nullptr, nullptr, none, 0, 1, 64);

    // 6. pack2: om2 = conv(off2); feat3 = lrelu(mdcn(feat2, om2)) -> S1
    if (big) {
        Ptr4 slots{omA0, omA1, omB0, omB1};
        ompack(S3, w_om2p, b_om2, slots, 4);
        mdcn_mfma<1><<<dim3(10, 180, 4), blk, 0, stream>>>(S2, slots, w_dcn2p, b_dcn2, S1);
    } else {
        Ptr4 slots{omA0, omA1, nullptr, nullptr};
        for (int pp = 0; pp < 2; ++pp) {
            ompack(S3 + 2 * pp * CHW, w_om2p, b_om2, slots, 2);
            mdcn_mfma<1><<<dim3(10, 180, 2), blk, 0, stream>>>(S2 + 2 * pp * CHW, slots,
                                                               w_dcn2p, b_dcn2, S1 + 2 * pp * CHW);
        }
    }

    // 7. corr = dot(conv(ref,ta1)+b, conv(feat3,ta2)+b) -> S3  (fully fused)
    tacorr_mfma<<<g4, blk, 0, stream>>>(S0, S1, w_ta1p, b_ta1, w_ta2p, b_ta2, corrf);

    // relocate ff weights out of d_out before the final conv overwrites it
    hipMemcpyAsync(ffw, w_ffp, 36864 * 2, hipMemcpyDeviceToDevice, stream);

    // 8. out = lrelu(conv(ref_t*corr, ff)) + ref  (f32 NCHW into d_out)
    conv_mfma<64, false, true, true, 2, 4, 4><<<g4w, blk, 0, stream>>>(
        S0, nullptr, ffw, b_ff, nullptr, corrf, ref, (float*)d_out, none, 0, 1, 64);
}